// Round 1
// baseline (276.973 us; speedup 1.0000x reference)
//
#include <hip/hip_runtime.h>

// Problem: AdapLoss — shape (8,1,160,160,160) fp32 pred/true.
// Per-sample: L2=mean(e^2), L1=mean(|e|), H=mean(huber(e, delta=5))
// per_sample = (L2<=1 || L2<L1^2) ? L2 : H ; out = mean over 8 samples.
//
// Memory-bound reduction: 262 MB read -> ~42us floor at 6.3 TB/s.

#define TPB 256
#define BPS 125                         // blocks per sample
constexpr int   F4_PER_SAMPLE = 1024000;   // 160^3 / 4
constexpr int   F4_PER_THREAD = 32;        // 125 * 256 * 32 = 1,024,000 exactly
constexpr double PER_SAMPLE_D = 4096000.0; // 160^3
constexpr float  DELTA = 5.0f;

__global__ __launch_bounds__(TPB) void adap_stage1(
    const float4* __restrict__ pred,
    const float4* __restrict__ truth,
    float* __restrict__ part)   // [8][BPS][3]
{
    const int s   = blockIdx.y;
    const int b   = blockIdx.x;
    const int tid = threadIdx.x;
    const int base = s * F4_PER_SAMPLE + b * (TPB * F4_PER_THREAD);

    float sum2 = 0.0f, sum1 = 0.0f, sumh = 0.0f;

    #pragma unroll 8
    for (int k = 0; k < F4_PER_THREAD; ++k) {
        const int idx = base + k * TPB + tid;     // coalesced: lane i -> consecutive float4
        float4 p = pred[idx];
        float4 t = truth[idx];

        float e0 = p.x - t.x, e1 = p.y - t.y, e2 = p.z - t.z, e3 = p.w - t.w;
        float a0 = fabsf(e0), a1 = fabsf(e1), a2 = fabsf(e2), a3 = fabsf(e3);

        sum2 += e0*e0 + e1*e1 + e2*e2 + e3*e3;
        sum1 += a0 + a1 + a2 + a3;

        float h0 = (a0 <= DELTA) ? 0.5f*e0*e0 : DELTA*(a0 - 0.5f*DELTA);
        float h1 = (a1 <= DELTA) ? 0.5f*e1*e1 : DELTA*(a1 - 0.5f*DELTA);
        float h2 = (a2 <= DELTA) ? 0.5f*e2*e2 : DELTA*(a2 - 0.5f*DELTA);
        float h3 = (a3 <= DELTA) ? 0.5f*e3*e3 : DELTA*(a3 - 0.5f*DELTA);
        sumh += h0 + h1 + h2 + h3;
    }

    // wave-64 butterfly reduce
    #pragma unroll
    for (int off = 32; off > 0; off >>= 1) {
        sum2 += __shfl_down(sum2, off, 64);
        sum1 += __shfl_down(sum1, off, 64);
        sumh += __shfl_down(sumh, off, 64);
    }

    __shared__ float w2[4], w1[4], wh[4];
    const int wave = tid >> 6, lane = tid & 63;
    if (lane == 0) { w2[wave] = sum2; w1[wave] = sum1; wh[wave] = sumh; }
    __syncthreads();
    if (tid == 0) {
        float a = 0.f, c = 0.f, h = 0.f;
        #pragma unroll
        for (int w = 0; w < 4; ++w) { a += w2[w]; c += w1[w]; h += wh[w]; }
        const int o = (s * BPS + b) * 3;
        part[o + 0] = a;
        part[o + 1] = c;
        part[o + 2] = h;
    }
}

__global__ __launch_bounds__(TPB) void adap_stage2(
    const float* __restrict__ part,   // [8][BPS][3]
    float* __restrict__ out)
{
    const int tid  = threadIdx.x;
    const int s    = tid >> 5;        // 8 samples x 32 lanes
    const int lane = tid & 31;

    double a = 0.0, b = 0.0, h = 0.0;
    for (int k = lane; k < BPS; k += 32) {
        const float* p = part + (s * BPS + k) * 3;
        a += (double)p[0];
        b += (double)p[1];
        h += (double)p[2];
    }
    #pragma unroll
    for (int off = 16; off > 0; off >>= 1) {
        a += __shfl_down(a, off, 32);
        b += __shfl_down(b, off, 32);
        h += __shfl_down(h, off, 32);
    }

    __shared__ double ps[8];
    if (lane == 0) {
        const double inv = 1.0 / PER_SAMPLE_D;
        double L2 = a * inv, L1 = b * inv, H = h * inv;
        bool use_l2 = (L2 <= 1.0) || (L2 < L1 * L1);
        ps[s] = use_l2 ? L2 : H;
    }
    __syncthreads();
    if (tid == 0) {
        double acc = 0.0;
        #pragma unroll
        for (int i = 0; i < 8; ++i) acc += ps[i];
        out[0] = (float)(acc * 0.125);
    }
}

extern "C" void kernel_launch(void* const* d_in, const int* in_sizes, int n_in,
                              void* d_out, int out_size, void* d_ws, size_t ws_size,
                              hipStream_t stream) {
    const float4* pred  = (const float4*)d_in[0];   // y_pred_logits fp32
    const float4* truth = (const float4*)d_in[1];   // y_true fp32
    float* part = (float*)d_ws;                     // 8*125*3 floats = 12 KB
    float* out  = (float*)d_out;

    dim3 grid1(BPS, 8);
    adap_stage1<<<grid1, TPB, 0, stream>>>(pred, truth, part);
    adap_stage2<<<1, TPB, 0, stream>>>(part, out);
}

// Round 2
// 273.228 us; speedup vs baseline: 1.0137x; 1.0137x over previous
//
#include <hip/hip_runtime.h>

// AdapLoss — (8,1,160,160,160) fp32. Memory-bound reduction, 262 MB read.
// R2: latency-bound fix — batch 8 loads in registers before consuming
// (was vmcnt(0)-serialized at VGPR=12), 2x grid for ~31 waves/CU.

#define TPB 256
#define BPS 250                          // blocks per sample
constexpr int    F4_PER_SAMPLE = 1024000;  // 160^3 / 4
constexpr int    F4_PER_BLOCK  = 4096;     // 16 float4/thread * 256 threads
constexpr double PER_SAMPLE_D  = 4096000.0;
constexpr float  DELTA = 5.0f;

__global__ __launch_bounds__(TPB, 8) void adap_stage1(
    const float4* __restrict__ pred,
    const float4* __restrict__ truth,
    float* __restrict__ part)   // [8][BPS][3]
{
    const int s   = blockIdx.y;
    const int b   = blockIdx.x;
    const int tid = threadIdx.x;
    const int base = s * F4_PER_SAMPLE + b * F4_PER_BLOCK + tid;

    float sum2 = 0.0f, sum1 = 0.0f, sumh = 0.0f;

    #pragma unroll 1
    for (int it = 0; it < 4; ++it) {
        const int o = base + it * (TPB * 4);
        float4 p[4], t[4];
        // 8 loads in flight before the first consume -> ~8KB/wave outstanding
        #pragma unroll
        for (int j = 0; j < 4; ++j) p[j] = pred[o + j * TPB];
        #pragma unroll
        for (int j = 0; j < 4; ++j) t[j] = truth[o + j * TPB];

        #pragma unroll
        for (int j = 0; j < 4; ++j) {
            float e0 = p[j].x - t[j].x, e1 = p[j].y - t[j].y;
            float e2 = p[j].z - t[j].z, e3 = p[j].w - t[j].w;
            float a0 = fabsf(e0), a1 = fabsf(e1), a2 = fabsf(e2), a3 = fabsf(e3);

            sum2 += e0*e0 + e1*e1 + e2*e2 + e3*e3;
            sum1 += a0 + a1 + a2 + a3;

            float h0 = (a0 <= DELTA) ? 0.5f*e0*e0 : DELTA*(a0 - 0.5f*DELTA);
            float h1 = (a1 <= DELTA) ? 0.5f*e1*e1 : DELTA*(a1 - 0.5f*DELTA);
            float h2 = (a2 <= DELTA) ? 0.5f*e2*e2 : DELTA*(a2 - 0.5f*DELTA);
            float h3 = (a3 <= DELTA) ? 0.5f*e3*e3 : DELTA*(a3 - 0.5f*DELTA);
            sumh += h0 + h1 + h2 + h3;
        }
    }

    // wave-64 butterfly reduce
    #pragma unroll
    for (int off = 32; off > 0; off >>= 1) {
        sum2 += __shfl_down(sum2, off, 64);
        sum1 += __shfl_down(sum1, off, 64);
        sumh += __shfl_down(sumh, off, 64);
    }

    __shared__ float w2[4], w1[4], wh[4];
    const int wave = tid >> 6, lane = tid & 63;
    if (lane == 0) { w2[wave] = sum2; w1[wave] = sum1; wh[wave] = sumh; }
    __syncthreads();
    if (tid == 0) {
        float a = 0.f, c = 0.f, h = 0.f;
        #pragma unroll
        for (int w = 0; w < 4; ++w) { a += w2[w]; c += w1[w]; h += wh[w]; }
        const int o = (s * BPS + b) * 3;
        part[o + 0] = a;
        part[o + 1] = c;
        part[o + 2] = h;
    }
}

__global__ __launch_bounds__(TPB) void adap_stage2(
    const float* __restrict__ part,   // [8][BPS][3]
    float* __restrict__ out)
{
    const int tid  = threadIdx.x;
    const int s    = tid >> 5;        // 8 samples x 32 lanes
    const int lane = tid & 31;

    double a = 0.0, b = 0.0, h = 0.0;
    for (int k = lane; k < BPS; k += 32) {
        const float* p = part + (s * BPS + k) * 3;
        a += (double)p[0];
        b += (double)p[1];
        h += (double)p[2];
    }
    #pragma unroll
    for (int off = 16; off > 0; off >>= 1) {
        a += __shfl_down(a, off, 32);
        b += __shfl_down(b, off, 32);
        h += __shfl_down(h, off, 32);
    }

    __shared__ double ps[8];
    if (lane == 0) {
        const double inv = 1.0 / PER_SAMPLE_D;
        double L2 = a * inv, L1 = b * inv, H = h * inv;
        bool use_l2 = (L2 <= 1.0) || (L2 < L1 * L1);
        ps[s] = use_l2 ? L2 : H;
    }
    __syncthreads();
    if (tid == 0) {
        double acc = 0.0;
        #pragma unroll
        for (int i = 0; i < 8; ++i) acc += ps[i];
        out[0] = (float)(acc * 0.125);
    }
}

extern "C" void kernel_launch(void* const* d_in, const int* in_sizes, int n_in,
                              void* d_out, int out_size, void* d_ws, size_t ws_size,
                              hipStream_t stream) {
    const float4* pred  = (const float4*)d_in[0];   // y_pred_logits fp32
    const float4* truth = (const float4*)d_in[1];   // y_true fp32
    float* part = (float*)d_ws;                     // 8*250*3 floats = 24 KB
    float* out  = (float*)d_out;

    dim3 grid1(BPS, 8);
    adap_stage1<<<grid1, TPB, 0, stream>>>(pred, truth, part);
    adap_stage2<<<1, TPB, 0, stream>>>(part, out);
}

// Round 4
// 248.095 us; speedup vs baseline: 1.1164x; 1.1013x over previous
//
#include <hip/hip_runtime.h>

// AdapLoss — (8,1,160,160,160) fp32. Memory-bound reduction, 262 MB read.
// R4 = R3 with the nontemporal-load type fixed (clang ext_vector_type(4)
// instead of HIP_vector_type). 16 x 16B loads fully batched in registers
// per thread, 128-VGPR budget (launch_bounds(256,4)), nt loads, 4000 blocks.

#define TPB 256
#define BPS 500                            // blocks per sample
constexpr int    F4_PER_SAMPLE = 1024000;  // 160^3 / 4
constexpr int    F4_PER_BLOCK  = 2048;     // 8 float4/thread * 256 threads
constexpr double PER_SAMPLE_D  = 4096000.0;
constexpr float  DELTA = 5.0f;

typedef float vf4 __attribute__((ext_vector_type(4)));

__global__ __launch_bounds__(TPB, 4) void adap_stage1(
    const vf4* __restrict__ pred,
    const vf4* __restrict__ truth,
    float* __restrict__ part)   // [8][BPS][3]
{
    const int s   = blockIdx.y;
    const int b   = blockIdx.x;
    const int tid = threadIdx.x;
    const int base = s * F4_PER_SAMPLE + b * F4_PER_BLOCK + tid;

    // Issue all 16 loads back-to-back, interleaved (p0,t0,p1,t1,...) so the
    // j-th consume only needs vmcnt(14-2j) — queue stays deep while consuming.
    vf4 p[8], t[8];
    #pragma unroll
    for (int j = 0; j < 8; ++j) {
        p[j] = __builtin_nontemporal_load(&pred [base + j * TPB]);
        t[j] = __builtin_nontemporal_load(&truth[base + j * TPB]);
    }

    float sum2 = 0.0f, sum1 = 0.0f, sumh = 0.0f;
    #pragma unroll
    for (int j = 0; j < 8; ++j) {
        float e0 = p[j].x - t[j].x, e1 = p[j].y - t[j].y;
        float e2 = p[j].z - t[j].z, e3 = p[j].w - t[j].w;
        float a0 = fabsf(e0), a1 = fabsf(e1), a2 = fabsf(e2), a3 = fabsf(e3);

        sum2 += e0*e0 + e1*e1 + e2*e2 + e3*e3;
        sum1 += a0 + a1 + a2 + a3;

        float h0 = (a0 <= DELTA) ? 0.5f*e0*e0 : DELTA*(a0 - 0.5f*DELTA);
        float h1 = (a1 <= DELTA) ? 0.5f*e1*e1 : DELTA*(a1 - 0.5f*DELTA);
        float h2 = (a2 <= DELTA) ? 0.5f*e2*e2 : DELTA*(a2 - 0.5f*DELTA);
        float h3 = (a3 <= DELTA) ? 0.5f*e3*e3 : DELTA*(a3 - 0.5f*DELTA);
        sumh += h0 + h1 + h2 + h3;
    }

    // wave-64 butterfly reduce
    #pragma unroll
    for (int off = 32; off > 0; off >>= 1) {
        sum2 += __shfl_down(sum2, off, 64);
        sum1 += __shfl_down(sum1, off, 64);
        sumh += __shfl_down(sumh, off, 64);
    }

    __shared__ float w2[4], w1[4], wh[4];
    const int wave = tid >> 6, lane = tid & 63;
    if (lane == 0) { w2[wave] = sum2; w1[wave] = sum1; wh[wave] = sumh; }
    __syncthreads();
    if (tid == 0) {
        float a = 0.f, c = 0.f, h = 0.f;
        #pragma unroll
        for (int w = 0; w < 4; ++w) { a += w2[w]; c += w1[w]; h += wh[w]; }
        const int o = (s * BPS + b) * 3;
        part[o + 0] = a;
        part[o + 1] = c;
        part[o + 2] = h;
    }
}

__global__ __launch_bounds__(TPB) void adap_stage2(
    const float* __restrict__ part,   // [8][BPS][3]
    float* __restrict__ out)
{
    const int tid  = threadIdx.x;
    const int s    = tid >> 5;        // 8 samples x 32 lanes
    const int lane = tid & 31;

    double a = 0.0, b = 0.0, h = 0.0;
    for (int k = lane; k < BPS; k += 32) {
        const float* p = part + (s * BPS + k) * 3;
        a += (double)p[0];
        b += (double)p[1];
        h += (double)p[2];
    }
    #pragma unroll
    for (int off = 16; off > 0; off >>= 1) {
        a += __shfl_down(a, off, 32);
        b += __shfl_down(b, off, 32);
        h += __shfl_down(h, off, 32);
    }

    __shared__ double ps[8];
    if (lane == 0) {
        const double inv = 1.0 / PER_SAMPLE_D;
        double L2 = a * inv, L1 = b * inv, H = h * inv;
        bool use_l2 = (L2 <= 1.0) || (L2 < L1 * L1);
        ps[s] = use_l2 ? L2 : H;
    }
    __syncthreads();
    if (tid == 0) {
        double acc = 0.0;
        #pragma unroll
        for (int i = 0; i < 8; ++i) acc += ps[i];
        out[0] = (float)(acc * 0.125);
    }
}

extern "C" void kernel_launch(void* const* d_in, const int* in_sizes, int n_in,
                              void* d_out, int out_size, void* d_ws, size_t ws_size,
                              hipStream_t stream) {
    const vf4* pred  = (const vf4*)d_in[0];   // y_pred_logits fp32
    const vf4* truth = (const vf4*)d_in[1];   // y_true fp32
    float* part = (float*)d_ws;               // 8*500*3 floats = 48 KB
    float* out  = (float*)d_out;

    dim3 grid1(BPS, 8);
    adap_stage1<<<grid1, TPB, 0, stream>>>(pred, truth, part);
    adap_stage2<<<1, TPB, 0, stream>>>(part, out);
}